// Round 9
// baseline (652.156 us; speedup 1.0000x reference)
//
#include <hip/hip_runtime.h>
#include <hip/hip_bf16.h>

typedef __hip_bfloat16 bf16t;
typedef short short8 __attribute__((ext_vector_type(8)));
typedef float f32x4 __attribute__((ext_vector_type(4)));

// B=4, S=1024, D=1024, H=16, E=64, N=32 slots; tokens T=4096; slot-rows TS=131072
// Inputs/outputs are FLOAT32 (per reference). Internal activations bf16 for MFMA.

__device__ __forceinline__ float featf(float x) { return x > 0.f ? x + 1.f : expf(x); }
__device__ __forceinline__ float ldf(const bf16t* p, size_t i) { return __bfloat162float(p[i]); }
__device__ __forceinline__ float ldf(const float* p, size_t i) { return p[i]; }
__device__ __forceinline__ void stf(bf16t* p, size_t i, float v) { p[i] = __float2bfloat16(v); }
__device__ __forceinline__ void stf(float* p, size_t i, float v) { p[i] = v; }
__device__ __forceinline__ float b2f(unsigned short u) {
    unsigned int x = ((unsigned int)u) << 16; float f; __builtin_memcpy(&f, &x, 4); return f;
}
__device__ __forceinline__ unsigned short f2b(float f) {
    bf16t h = __float2bfloat16(f); unsigned short u; __builtin_memcpy(&u, &h, 2); return u;
}
// async global->LDS, 16B per lane; lds dest = wave-uniform base + lane*16
__device__ __forceinline__ void gl_lds16(const short* g, short* l) {
    __builtin_amdgcn_global_load_lds((const __attribute__((address_space(1))) unsigned int*)g,
                                     (__attribute__((address_space(3))) unsigned int*)l, 16, 0, 0);
}
#define MFMA16(a, b, c) __builtin_amdgcn_mfma_f32_16x16x32_bf16((a), (b), (c), 0, 0, 0)

// ---------------- sentinel fill (ws too small diagnostic) ----------------
__global__ __launch_bounds__(256) void fill_k(float* __restrict__ out, int n, float v) {
    int i = blockIdx.x * 256 + threadIdx.x;
    if (i < n) out[i] = v;
}

// ---------------- transpose + fp32->bf16 convert (tiled; big weights) ----------------
__global__ __launch_bounds__(256) void transpose_k(const float* __restrict__ W,
                                                   bf16t* __restrict__ Wt,
                                                   int R, int C) {
    __shared__ bf16t tile[32][33];
    int c0 = blockIdx.x * 32, r0 = blockIdx.y * 32;
    int tx = threadIdx.x, ty = threadIdx.y; // 32 x 8
    #pragma unroll
    for (int i = 0; i < 32; i += 8) {
        int r = r0 + ty + i, c = c0 + tx;
        if (r < R && c < C) tile[ty + i][tx] = __float2bfloat16(W[(size_t)r * C + c]);
    }
    __syncthreads();
    #pragma unroll
    for (int i = 0; i < 32; i += 8) {
        int r = c0 + ty + i, c = r0 + tx;
        if (r < C && c < R) Wt[(size_t)r * R + c] = tile[tx][ty + i];
    }
}

// ---------------- fused small-weight prep (transposes + WtqI + bias concat) ----------------
__global__ __launch_bounds__(256) void small_prep_k(const float* __restrict__ Wtk,
                                                    const float* __restrict__ Wtv,
                                                    const float* __restrict__ Wtq,
                                                    const float* __restrict__ Wl1,
                                                    const float* __restrict__ Wl2,
                                                    const float* __restrict__ Wsp,
                                                    const float* __restrict__ bk,
                                                    const float* __restrict__ bv,
                                                    const float* __restrict__ bip,
                                                    const float* __restrict__ bq,
                                                    bf16t* __restrict__ WtkT,
                                                    bf16t* __restrict__ WtvT,
                                                    bf16t* __restrict__ WtqI,
                                                    bf16t* __restrict__ Wl1T,
                                                    bf16t* __restrict__ Wl2T,
                                                    bf16t* __restrict__ WspT,
                                                    float* __restrict__ bcat) {
    int b = blockIdx.x, tid = threadIdx.x;
    if (b == 0) {
        for (int i = tid; i < 4096; i += 256) { int c = i >> 6, r = i & 63; WtkT[i] = __float2bfloat16(Wtk[r * 64 + c]); }
    } else if (b == 1) {
        for (int i = tid; i < 4096; i += 256) { int c = i >> 6, r = i & 63; WtvT[i] = __float2bfloat16(Wtv[r * 64 + c]); }
    } else if (b == 2) {
        for (int i = tid; i < 8192; i += 256) {
            int e = i >> 7, k = i & 127;
            float v = (k < 64) ? Wtq[k * 64 + e] : ((k - 64 == e) ? 1.f : 0.f);
            WtqI[i] = __float2bfloat16(v);
        }
    } else if (b == 3) {
        for (int i = tid; i < 8192; i += 256) { int n = i >> 6, k = i & 63; Wl1T[i] = __float2bfloat16(Wl1[k * 128 + n]); }
    } else if (b == 4) {
        for (int i = tid; i < 8192; i += 256) { int n = i >> 7, k = i & 127; Wl2T[i] = __float2bfloat16(Wl2[k * 64 + n]); }
    } else if (b == 5) {
        for (int i = tid; i < 8192; i += 256) { int n = i >> 7, k = i & 127; WspT[i] = __float2bfloat16(Wsp[k * 64 + n]); }
    } else {
        for (int i = tid; i < 5120; i += 256) {
            float v;
            if (i < 1024) v = bk[i];
            else if (i < 2048) v = bv[i - 1024];
            else if (i < 4096) v = bip[i - 2048];
            else v = bq[i - 4096];
            bcat[i] = v;
        }
    }
}

// ---------------- LayerNorm over D=1024 (fp32 in, bf16 out), one block/token ----------------
__global__ __launch_bounds__(256) void ln_kernel(const float* __restrict__ X,
                                                 const float* __restrict__ g,
                                                 const float* __restrict__ b,
                                                 bf16t* __restrict__ Y) {
    int t = blockIdx.x, tid = threadIdx.x;
    size_t base = (size_t)t * 1024 + tid * 4;
    float v0 = X[base + 0], v1 = X[base + 1], v2 = X[base + 2], v3 = X[base + 3];
    float s = v0 + v1 + v2 + v3;
    float q = v0 * v0 + v1 * v1 + v2 * v2 + v3 * v3;
    __shared__ float rs[4], rq[4];
    for (int o = 32; o > 0; o >>= 1) { s += __shfl_down(s, o); q += __shfl_down(q, o); }
    int wid = tid >> 6, lane = tid & 63;
    if (lane == 0) { rs[wid] = s; rq[wid] = q; }
    __syncthreads();
    float S = rs[0] + rs[1] + rs[2] + rs[3];
    float Q = rq[0] + rq[1] + rq[2] + rq[3];
    float mean = S * (1.f / 1024.f);
    float var = Q * (1.f / 1024.f) - mean * mean;
    float rstd = rsqrtf(var + 1e-5f);
    int c = tid * 4;
    stf(Y, base + 0, (v0 - mean) * rstd * g[c + 0] + b[c + 0]);
    stf(Y, base + 1, (v1 - mean) * rstd * g[c + 1] + b[c + 1]);
    stf(Y, base + 2, (v2 - mean) * rstd * g[c + 2] + b[c + 2]);
    stf(Y, base + 3, (v3 - mean) * rstd * g[c + 3] + b[c + 3]);
}

// ======= 128x128-tile MFMA GEMM (m97 pattern): C = A[M,K] @ Bt[N,K]^T + bias, epilogues =====
// MODE 0: v   4: relu(v)   5: v+add
template <int MODE, typename TC, typename TADD>
__global__ __launch_bounds__(256) void gemm128_k(const bf16t* __restrict__ A,
                                                 const bf16t* __restrict__ Bt,
                                                 const float* __restrict__ bias,
                                                 const TADD* __restrict__ add,
                                                 TC* __restrict__ C,
                                                 int M, int N, int K, int ldC) {
    __shared__ short As[128 * 32];
    __shared__ short Bs[128 * 32];
    int tid = threadIdx.x;
    int wave = tid >> 6, lane = tid & 63;
    int l16 = lane & 15, quad = lane >> 4;
    int tilesM = M >> 7;
    int tm = blockIdx.x % tilesM;           // column-major: consecutive blocks share B tile
    int tn = blockIdx.x / tilesM;
    int wm = wave >> 1, wn = wave & 1;

    int lrow = lane >> 2;
    int lseg = (lane & 3) * 8;
    const short* Ag = (const short*)A + (size_t)(tm * 128 + wave * 32 + lrow) * K + lseg;
    const short* Ag2 = Ag + (size_t)16 * K;
    const short* Bg = (const short*)Bt + (size_t)(tn * 128 + wave * 32 + lrow) * K + lseg;
    const short* Bg2 = Bg + (size_t)16 * K;
    short* Asw = As + (wave * 32) * 32;
    short* Asw2 = Asw + 16 * 32;
    short* Bsw = Bs + (wave * 32) * 32;
    short* Bsw2 = Bsw + 16 * 32;

    f32x4 acc[4][4] = {};
    for (int k0 = 0; k0 < K; k0 += 32) {
        gl_lds16(Ag + k0, Asw);
        gl_lds16(Ag2 + k0, Asw2);
        gl_lds16(Bg + k0, Bsw);
        gl_lds16(Bg2 + k0, Bsw2);
        __syncthreads();
        short8 av[4], bv[4];
        #pragma unroll
        for (int i = 0; i < 4; i++)
            av[i] = *(const short8*)(As + (wm * 64 + i * 16 + l16) * 32 + quad * 8);
        #pragma unroll
        for (int j = 0; j < 4; j++)
            bv[j] = *(const short8*)(Bs + (wn * 64 + j * 16 + l16) * 32 + quad * 8);
        #pragma unroll
        for (int i = 0; i < 4; i++)
            #pragma unroll
            for (int j = 0; j < 4; j++)
                acc[i][j] = MFMA16(av[i], bv[j], acc[i][j]);
        __syncthreads();
    }

    #pragma unroll
    for (int j = 0; j < 4; j++) {
        int col = tn * 128 + wn * 64 + j * 16 + l16;
        float bcol = bias[col];
        #pragma unroll
        for (int i = 0; i < 4; i++) {
            int row0 = tm * 128 + wm * 64 + i * 16 + quad * 4;
            #pragma unroll
            for (int r = 0; r < 4; r++) {
                int row = row0 + r;
                float v = acc[i][j][r] + bcol;
                float outv;
                if constexpr (MODE == 0) outv = v;
                else if constexpr (MODE == 4) outv = fmaxf(v, 0.f);
                else if constexpr (MODE == 5) outv = v + ldf(add, (size_t)row * N + col);
                else outv = v;
                stf(C, (size_t)row * ldC + col, outv);
            }
        }
    }
}

// ======= merged projection GEMM: [xn] @ [Wk|Wv|Wip|Wq]^T (N=5120), split epilogue =========
__global__ __launch_bounds__(256) void gemm_proj_k(const bf16t* __restrict__ A,
                                                   const bf16t* __restrict__ Bt,
                                                   const float* __restrict__ bias,
                                                   bf16t* __restrict__ kv0,
                                                   bf16t* __restrict__ inp,
                                                   bf16t* __restrict__ qf) {
    __shared__ short As[128 * 32];
    __shared__ short Bs[128 * 32];
    const int K = 1024;
    int tid = threadIdx.x;
    int wave = tid >> 6, lane = tid & 63;
    int l16 = lane & 15, quad = lane >> 4;
    int tm = blockIdx.x & 31;
    int tn = blockIdx.x >> 5;
    int wm = wave >> 1, wn = wave & 1;

    int lrow = lane >> 2;
    int lseg = (lane & 3) * 8;
    const short* Ag = (const short*)A + (size_t)(tm * 128 + wave * 32 + lrow) * K + lseg;
    const short* Ag2 = Ag + (size_t)16 * K;
    const short* Bg = (const short*)Bt + (size_t)(tn * 128 + wave * 32 + lrow) * K + lseg;
    const short* Bg2 = Bg + (size_t)16 * K;
    short* Asw = As + (wave * 32) * 32;
    short* Asw2 = Asw + 16 * 32;
    short* Bsw = Bs + (wave * 32) * 32;
    short* Bsw2 = Bsw + 16 * 32;

    f32x4 acc[4][4] = {};
    for (int k0 = 0; k0 < K; k0 += 32) {
        gl_lds16(Ag + k0, Asw);
        gl_lds16(Ag2 + k0, Asw2);
        gl_lds16(Bg + k0, Bsw);
        gl_lds16(Bg2 + k0, Bsw2);
        __syncthreads();
        short8 av[4], bv[4];
        #pragma unroll
        for (int i = 0; i < 4; i++)
            av[i] = *(const short8*)(As + (wm * 64 + i * 16 + l16) * 32 + quad * 8);
        #pragma unroll
        for (int j = 0; j < 4; j++)
            bv[j] = *(const short8*)(Bs + (wn * 64 + j * 16 + l16) * 32 + quad * 8);
        #pragma unroll
        for (int i = 0; i < 4; i++)
            #pragma unroll
            for (int j = 0; j < 4; j++)
                acc[i][j] = MFMA16(av[i], bv[j], acc[i][j]);
        __syncthreads();
    }

    #pragma unroll
    for (int j = 0; j < 4; j++) {
        int col = tn * 128 + wn * 64 + j * 16 + l16;
        float bcol = bias[col];
        #pragma unroll
        for (int i = 0; i < 4; i++) {
            int row0 = tm * 128 + wm * 64 + i * 16 + quad * 4;
            #pragma unroll
            for (int r = 0; r < 4; r++) {
                int row = row0 + r;
                float v = acc[i][j][r] + bcol;
                if (tn < 16) stf(kv0, (size_t)row * 2048 + col, v);
                else if (tn < 32) stf(inp, (size_t)row * 2048 + (col - 2048), v);
                else stf(qf, (size_t)row * 1024 + (col - 4096), featf(v * 0.125f));
            }
        }
    }
}

// ---------------- streaming MFMA GEMM (K<=128 fat-M cases), fused epilogues ----------
// MODE 0: v   1: feat(v)   7: per-token transpose store [t][e][w] (vvT)
template <int MODE, typename TC>
__global__ __launch_bounds__(256) void gemm_k(const bf16t* __restrict__ A,
                                              const bf16t* __restrict__ Bt,
                                              const float* __restrict__ bias,
                                              TC* __restrict__ C,
                                              int M, int N, int K, int ldC) {
    int wave = threadIdx.x >> 6;
    int lane = threadIdx.x & 63;
    int tilesN = N >> 6;
    int tiles = (M >> 6) * tilesN;
    int tile = blockIdx.x * 4 + wave;
    if (tile >= tiles) return;
    int tm = tile / tilesN, tn = tile - tm * tilesN;
    int l16 = lane & 15, quad = lane >> 4;

    f32x4 acc[4][4] = {};
    const short* Ab = (const short*)A + (size_t)(tm * 64 + l16) * K;
    const short* Bb = (const short*)Bt + (size_t)(tn * 64 + l16) * K;

    for (int k0 = 0; k0 < K; k0 += 32) {
        int ka = k0 + quad * 8;
        short8 av[4], bv[4];
        #pragma unroll
        for (int i = 0; i < 4; i++) av[i] = *(const short8*)(Ab + (size_t)i * 16 * K + ka);
        #pragma unroll
        for (int j = 0; j < 4; j++) bv[j] = *(const short8*)(Bb + (size_t)j * 16 * K + ka);
        #pragma unroll
        for (int i = 0; i < 4; i++)
            #pragma unroll
            for (int j = 0; j < 4; j++)
                acc[i][j] = MFMA16(av[i], bv[j], acc[i][j]);
    }

    #pragma unroll
    for (int j = 0; j < 4; j++) {
        int col = tn * 64 + j * 16 + l16;
        float bcol = bias[col];
        #pragma unroll
        for (int i = 0; i < 4; i++) {
            int row0 = tm * 64 + i * 16 + quad * 4;
            #pragma unroll
            for (int r = 0; r < 4; r++) {
                int row = row0 + r;
                float v = acc[i][j][r] + bcol;
                if constexpr (MODE == 7) {
                    stf(C, (size_t)(row >> 5) * 2048 + (size_t)col * 32 + (row & 31), v);
                } else {
                    float outv;
                    if constexpr (MODE == 0) outv = v;
                    else if constexpr (MODE == 1) outv = featf(v);
                    else outv = v;
                    stf(C, (size_t)row * ldC + col, outv);
                }
            }
        }
    }
}

// ---------------- fused concat GEMM: C[TS,64] = [A1|A2] @ Bt[64,128]^T + bias -------------
__global__ __launch_bounds__(256) void gemm_cat_k(const bf16t* __restrict__ A1,
                                                  const bf16t* __restrict__ A2,
                                                  const bf16t* __restrict__ Bt,
                                                  const float* __restrict__ bias,
                                                  bf16t* __restrict__ C, int M) {
    int wave = threadIdx.x >> 6;
    int lane = threadIdx.x & 63;
    int tiles = M >> 6;
    int tile = blockIdx.x * 4 + wave;
    if (tile >= tiles) return;
    int tm = tile;
    int l16 = lane & 15, quad = lane >> 4;
    f32x4 acc[4][4] = {};
    #pragma unroll
    for (int p = 0; p < 2; p++) {
        const short* Ab = (const short*)(p ? A2 : A1) + (size_t)(tm * 64 + l16) * 64;
        const short* Bb = (const short*)Bt + (size_t)l16 * 128 + p * 64;
        #pragma unroll
        for (int k0 = 0; k0 < 64; k0 += 32) {
            int ka = k0 + quad * 8;
            short8 av[4], bv[4];
            #pragma unroll
            for (int i = 0; i < 4; i++) av[i] = *(const short8*)(Ab + (size_t)i * 16 * 64 + ka);
            #pragma unroll
            for (int j = 0; j < 4; j++) bv[j] = *(const short8*)(Bb + (size_t)j * 16 * 128 + ka);
            #pragma unroll
            for (int i = 0; i < 4; i++)
                #pragma unroll
                for (int j = 0; j < 4; j++)
                    acc[i][j] = MFMA16(av[i], bv[j], acc[i][j]);
        }
    }
    #pragma unroll
    for (int j = 0; j < 4; j++) {
        int col = j * 16 + l16;
        float bcol = bias[col];
        #pragma unroll
        for (int i = 0; i < 4; i++) {
            int row0 = tm * 64 + i * 16 + quad * 4;
            #pragma unroll
            for (int r = 0; r < 4; r++)
                C[(size_t)(row0 + r) * 64 + col] = __float2bfloat16(acc[i][j][r] + bcol);
        }
    }
}

// ========== fused slot loop: all 3 iterations, TWO waves per token (16 rows each) ==========
// block = 4 waves = 2 tokens; token-shared LDS for qq/attnT/colsums; 3 barriers/iter.
__global__ __launch_bounds__(256) void slot_all_k(const bf16t* __restrict__ kv0,
                                                  const bf16t* __restrict__ kk,
                                                  const bf16t* __restrict__ vvT,
                                                  const bf16t* __restrict__ WtqI,
                                                  const float* __restrict__ btq,
                                                  const float* __restrict__ lnpg,
                                                  const float* __restrict__ lnpb,
                                                  const bf16t* __restrict__ Wl1T,
                                                  const float* __restrict__ bl1,
                                                  const bf16t* __restrict__ Wl2T,
                                                  const float* __restrict__ bl2,
                                                  bf16t* __restrict__ slots_out) {
    __shared__ short slotsW[4][16 * 72];   // per-wave slots rows (16) pitch 72
    __shared__ short Xt[2][32 * 72];       // per-token scratch: qq / attnT / hln / h1
    __shared__ float csum[2][2][32];       // per-token per-half column sums
    int wave = threadIdx.x >> 6, lane = threadIdx.x & 63;
    int l16 = lane & 15, quad = lane >> 4;
    int tok = wave >> 1, half = wave & 1;
    int t = blockIdx.x * 2 + tok;
    int r0 = half * 16;                    // this wave's slot-row offset
    short* S = slotsW[wave];
    short* X = Xt[tok];
    size_t tbase = (size_t)t * 2048;

    // slots := kv0 rows [r0, r0+16)
    {
        const short* src = (const short*)kv0 + tbase + (size_t)r0 * 64;
        #pragma unroll
        for (int p = 0; p < 2; p++) {
            int idx = p * 512 + lane * 8;
            int row = idx >> 6, col = idx & 63;
            *(short8*)(S + row * 72 + col) = *(const short8*)(src + idx);
        }
    }
    // kk (w rows of own half) and kv0 (n rows of own half) fragments in registers
    short8 kkf[2], kvf[2];
    #pragma unroll
    for (int k0 = 0; k0 < 2; k0++) {
        size_t fo = tbase + (size_t)(r0 + l16) * 64 + k0 * 32 + quad * 8;
        kkf[k0] = *(const short8*)((const short*)kk + fo);
        kvf[k0] = *(const short8*)((const short*)kv0 + fo);
    }

    float btqv[4], bl2v[4], lgv[4], lbv[4], bl1v[8];
    #pragma unroll
    for (int j = 0; j < 4; j++) {
        btqv[j] = btq[j * 16 + l16]; bl2v[j] = bl2[j * 16 + l16];
        lgv[j] = lnpg[j * 16 + l16]; lbv[j] = lnpb[j * 16 + l16];
    }
    #pragma unroll
    for (int j = 0; j < 8; j++) bl1v[j] = bl1[j * 16 + l16];

    for (int it = 0; it < 3; it++) {
        // ---- qq rows own half = feat(([slots|kv0] @ WtqI^T + btq)/8) -> X[n][e] pitch 72
        {
            f32x4 aq[4] = {};
            #pragma unroll
            for (int k0 = 0; k0 < 4; k0++) {
                short8 af = (k0 < 2) ? *(const short8*)(S + l16 * 72 + k0 * 32 + quad * 8)
                                     : kvf[k0 - 2];
                #pragma unroll
                for (int j = 0; j < 4; j++) {
                    short8 bf_ = *(const short8*)((const short*)WtqI + (size_t)(j * 16 + l16) * 128 + k0 * 32 + quad * 8);
                    aq[j] = MFMA16(af, bf_, aq[j]);
                }
            }
            #pragma unroll
            for (int j = 0; j < 4; j++)
                #pragma unroll
                for (int r = 0; r < 4; r++) {
                    int n = r0 + quad * 4 + r, e = j * 16 + l16;
                    X[n * 72 + e] = (short)f2b(featf((aq[j][r] + btqv[j]) * 0.125f));
                }
        }
        __syncthreads();   // qq complete (both halves)
        // ---- logits rows w own half: kk @ qq^T ; softmax over n; partial colsums
        f32x4 al[2] = {};
        #pragma unroll
        for (int k0 = 0; k0 < 2; k0++) {
            #pragma unroll
            for (int j = 0; j < 2; j++) {
                short8 bf_ = *(const short8*)(X + (j * 16 + l16) * 72 + k0 * 32 + quad * 8);
                al[j] = MFMA16(kkf[k0], bf_, al[j]);
            }
        }
        #pragma unroll
        for (int r = 0; r < 4; r++) {
            float m = fmaxf(al[0][r], al[1][r]);
            #pragma unroll
            for (int d = 1; d < 16; d <<= 1) m = fmaxf(m, __shfl_xor(m, d));
            float e0 = expf(al[0][r] - m), e1 = expf(al[1][r] - m);
            float s = e0 + e1;
            #pragma unroll
            for (int d = 1; d < 16; d <<= 1) s += __shfl_xor(s, d);
            float inv = 1.f / s;
            al[0][r] = e0 * inv + 1e-6f;
            al[1][r] = e1 * inv + 1e-6f;
        }
        #pragma unroll
        for (int j = 0; j < 2; j++) {
            float cs = al[j][0] + al[j][1] + al[j][2] + al[j][3];
            cs += __shfl_xor(cs, 16);
            cs += __shfl_xor(cs, 32);
            if (quad == 0) csum[tok][half][j * 16 + l16] = cs;
        }
        __syncthreads();   // qq reads done + csum visible
        // ---- normalize over w; write attnT[n][w] (all n rows, own w cols) pitch 72
        #pragma unroll
        for (int j = 0; j < 2; j++) {
            int n = j * 16 + l16;
            float inv = 1.f / (csum[tok][0][n] + csum[tok][1][n]);
            #pragma unroll
            for (int r = 0; r < 4; r++)
                X[n * 72 + r0 + quad * 4 + r] = (short)f2b(al[j][r] * inv);
        }
        __syncthreads();   // attnT complete
        // ---- upd rows n own half = attnT @ vvT
        f32x4 au[4] = {};
        {
            short8 af = *(const short8*)(X + (r0 + l16) * 72 + quad * 8);
            #pragma unroll
            for (int j = 0; j < 4; j++) {
                short8 bf_ = *(const short8*)((const short*)vvT + tbase + (size_t)(j * 16 + l16) * 32 + quad * 8);
                au[j] = MFMA16(af, bf_, au[j]);
            }
        }
        // ---- LN over e per row n -> X rows own half pitch 72
        #pragma unroll
        for (int r = 0; r < 4; r++) {
            float s1 = 0.f, s2 = 0.f;
            #pragma unroll
            for (int j = 0; j < 4; j++) { float u = au[j][r]; s1 += u; s2 += u * u; }
            #pragma unroll
            for (int d = 1; d < 16; d <<= 1) { s1 += __shfl_xor(s1, d); s2 += __shfl_xor(s2, d); }
            float mean = s1 * (1.f / 64.f);
            float var = s2 * (1.f / 64.f) - mean * mean;
            float rstd = rsqrtf(var + 1e-5f);
            int n = r0 + quad * 4 + r;
            #pragma unroll
            for (int j = 0; j < 4; j++)
                X[n * 72 + j * 16 + l16] = (short)f2b((au[j][r] - mean) * rstd * lgv[j] + lbv[j]);
        }
        // ---- MLP (chunked, rows own half): preload hln A-frags, 2 chunks of 64 h1-cols
        short8 a1[2];
        #pragma unroll
        for (int k0 = 0; k0 < 2; k0++)
            a1[k0] = *(const short8*)(X + (r0 + l16) * 72 + k0 * 32 + quad * 8);
        f32x4 ac2[4] = {};
        #pragma unroll
        for (int c = 0; c < 2; c++) {
            f32x4 ac1[4] = {};
            #pragma unroll
            for (int k0 = 0; k0 < 2; k0++)
                #pragma unroll
                for (int j = 0; j < 4; j++) {
                    short8 bf_ = *(const short8*)((const short*)Wl1T + (size_t)((c * 4 + j) * 16 + l16) * 64 + k0 * 32 + quad * 8);
                    ac1[j] = MFMA16(a1[k0], bf_, ac1[j]);
                }
            #pragma unroll
            for (int j = 0; j < 4; j++)
                #pragma unroll
                for (int r = 0; r < 4; r++) {
                    int n = r0 + quad * 4 + r;
                    X[n * 72 + j * 16 + l16] = (short)f2b(fmaxf(ac1[j][r] + bl1v[c * 4 + j], 0.f));
                }
            #pragma unroll
            for (int kc = 0; kc < 2; kc++) {
                short8 a2 = *(const short8*)(X + (r0 + l16) * 72 + kc * 32 + quad * 8);
                int k1 = c * 2 + kc;
                #pragma unroll
                for (int j = 0; j < 4; j++) {
                    short8 bf_ = *(const short8*)((const short*)Wl2T + (size_t)(j * 16 + l16) * 128 + k1 * 32 + quad * 8);
                    ac2[j] = MFMA16(a2, bf_, ac2[j]);
                }
            }
        }
        // ---- slot update (own rows; local row = quad*4+r)
        #pragma unroll
        for (int j = 0; j < 4; j++)
            #pragma unroll
            for (int r = 0; r < 4; r++) {
                int nl = quad * 4 + r, e = j * 16 + l16;
                float old = b2f((unsigned short)S[nl * 72 + e]);
                S[nl * 72 + e] = (short)f2b(old + (ac2[j][r] + bl2v[j]) * (1.f / 64.f));
            }
    }
    // write final slots (own 16 rows)
    {
        short* dst = (short*)slots_out + tbase + (size_t)r0 * 64;
        #pragma unroll
        for (int p = 0; p < 2; p++) {
            int idx = p * 512 + lane * 8;
            int row = idx >> 6, col = idx & 63;
            *(short8*)(dst + idx) = *(const short8*)(S + row * 72 + col);
        }
    }
}

// ---------------- Kmat[bh] = kf^T @ v2 over s (MFMA, no atomics); ksum[bh] = sum_s kf ------
__global__ __launch_bounds__(256) void kv_outer_k(const bf16t* __restrict__ slotsO,
                                                  float* __restrict__ Kmat,
                                                  float* __restrict__ ksum) {
    __shared__ short kfT[64 * 72];   // [e][s] pitch 72
    __shared__ short v2T[64 * 72];
    __shared__ float ksred[8][64];
    int bh = blockIdx.x;
    int b = bh >> 4, h = bh & 15;
    int tid = threadIdx.x;
    int wave = tid >> 6, lane = tid & 63;
    int l16 = lane & 15, quad = lane >> 4;
    int m0 = wave * 16;

    int sgrp = tid >> 5;
    int e0 = (tid & 31) * 2;
    float ks0 = 0.f, ks1 = 0.f;
    f32x4 acc[4];
    #pragma unroll
    for (int j = 0; j < 4; j++) acc[j] = (f32x4){0.f, 0.f, 0.f, 0.f};

    for (int tile = 0; tile < 16; tile++) {
        #pragma unroll
        for (int p = 0; p < 8; p++) {
            int sl = p * 8 + sgrp;
            size_t row = ((size_t)(b * 1024 + tile * 64 + sl)) * 2048;
            unsigned int dk = *(const unsigned int*)((const unsigned short*)slotsO + row + h * 64 + e0);
            float f0 = featf(b2f((unsigned short)(dk & 0xffff)));
            float f1 = featf(b2f((unsigned short)(dk >> 16)));
            ks0 += f0; ks1 += f1;
            kfT[e0 * 72 + sl] = (short)f2b(f0);
            kfT[(e0 + 1) * 72 + sl] = (short)f2b(f1);
            unsigned int dv = *(const unsigned int*)((const unsigned short*)slotsO + row + (16 + h) * 64 + e0);
            v2T[e0 * 72 + sl] = (short)(dv & 0xffff);
            v2T[(e0 + 1) * 72 + sl] = (short)(dv >> 16);
        }
        __syncthreads();
        #pragma unroll
        for (int k2 = 0; k2 < 2; k2++) {
            short8 a = *(const short8*)(kfT + (m0 + l16) * 72 + k2 * 32 + quad * 8);
            #pragma unroll
            for (int j = 0; j < 4; j++) {
                short8 bv = *(const short8*)(v2T + (j * 16 + l16) * 72 + k2 * 32 + quad * 8);
                acc[j] = MFMA16(a, bv, acc[j]);
            }
        }
        __syncthreads();
    }

    float* Km = Kmat + (size_t)bh * 4096;
    #pragma unroll
    for (int j = 0; j < 4; j++)
        #pragma unroll
        for (int r = 0; r < 4; r++)
            Km[(m0 + quad * 4 + r) * 64 + j * 16 + l16] = acc[j][r];

    ksred[sgrp][e0] = ks0;
    ksred[sgrp][e0 + 1] = ks1;
    __syncthreads();
    if (tid < 64) {
        float s = 0.f;
        #pragma unroll
        for (int r = 0; r < 8; r++) s += ksred[r][tid];
        ksum[bh * 64 + tid] = s;
    }
}

// ---------------- attn_out[t, h*64+j] = (qf_th @ Kmat[bh]) / (qf_th . ksum[bh] + 1e-5) ----
__global__ __launch_bounds__(256) void attn_out_k(const bf16t* __restrict__ qf,
                                                  const float* __restrict__ Kmat,
                                                  const float* __restrict__ ksum,
                                                  bf16t* __restrict__ out) {
    int t = blockIdx.x, tid = threadIdx.x;
    int b = t >> 10;
    __shared__ float q[16 * 65];
    __shared__ float dinv[16];
    for (int i = tid; i < 1024; i += 256) {
        int h = i >> 6, e = i & 63;
        q[h * 65 + e] = __bfloat162float(qf[(size_t)t * 1024 + i]);
    }
    __syncthreads();
    if (tid < 16) {
        int bh = b * 16 + tid;
        float d = 0.f;
        for (int e = 0; e < 64; e++) d += q[tid * 65 + e] * ksum[bh * 64 + e];
        dinv[tid] = 1.f / (d + 1e-5f);
    }
    __syncthreads();
    int h = tid >> 4, j0 = (tid & 15) * 4;
    const float* Km = Kmat + (size_t)(b * 16 + h) * 4096;
    float a0 = 0.f, a1 = 0.f, a2 = 0.f, a3 = 0.f;
    for (int e = 0; e < 64; e++) {
        float qe = q[h * 65 + e];
        const float* kr = Km + e * 64 + j0;
        a0 += qe * kr[0]; a1 += qe * kr[1]; a2 += qe * kr[2]; a3 += qe * kr[3];
    }
    float di = dinv[h];
    size_t ob = (size_t)t * 1024 + h * 64 + j0;
    out[ob + 0] = __float2bfloat16(a0 * di);
    out[ob + 1] = __float2bfloat16(a1 * di);
    out[ob + 2] = __float2bfloat16(a2 * di);
    out[ob + 3] = __float2bfloat16(a3 * di);
}

// ======================= host =======================
#define LAUNCH_GEMM(MODE, TCT, A_, Bt_, bias_, C_, M_, N_, K_, ldC_)                         \
    do {                                                                                     \
        int tiles__ = ((M_) >> 6) * ((N_) >> 6);                                             \
        gemm_k<MODE, TCT><<<(tiles__ + 3) / 4, 256, 0, stream>>>(                            \
            (const bf16t*)(A_), (const bf16t*)(Bt_), (const float*)(bias_),                  \
            (TCT*)(C_), (M_), (N_), (K_), (ldC_));                                           \
    } while (0)

#define LAUNCH_GEMM128(MODE, TCT, TADDT, A_, Bt_, bias_, add_, C_, M_, N_, K_, ldC_)         \
    do {                                                                                     \
        int tiles__ = ((M_) >> 7) * ((N_) >> 7);                                             \
        gemm128_k<MODE, TCT, TADDT><<<tiles__, 256, 0, stream>>>(                            \
            (const bf16t*)(A_), (const bf16t*)(Bt_), (const float*)(bias_),                  \
            (const TADDT*)(add_), (TCT*)(C_), (M_), (N_), (K_), (ldC_));                     \
    } while (0)

extern "C" void kernel_launch(void* const* d_in, const int* in_sizes, int n_in,
                              void* d_out, int out_size, void* d_ws, size_t ws_size,
                              hipStream_t stream) {
    (void)in_sizes; (void)n_in;
    const float* x    = (const float*)d_in[0];
    const float* ln1g = (const float*)d_in[1];
    const float* ln1b = (const float*)d_in[2];
    const float* ln2g = (const float*)d_in[3];
    const float* ln2b = (const float*)d_in[4];
    const float* Wq  = (const float*)d_in[5];  const float* bq  = (const float*)d_in[6];
    const float* Wk  = (const float*)d_in[7];  const float* bk  = (const float*)d_in[8];
    const float* Wv  = (const float*)d_in[9];  const float* bv  = (const float*)d_in[10];
    const float* Wf  = (const float*)d_in[11]; const float* bWf = (const float*)d_in[12];
    const float* Wr1 = (const float*)d_in[13]; const float* br1 = (const float*)d_in[14];
    const float* Wr2 = (const float*)d_in[15]; const float* br2 = (const float*)d_in[16];
    const float* Wip = (const float*)d_in[17]; const float* bip = (const float*)d_in[18];
    const float* Wtq = (const float*)d_in[19]; const float* btq = (const float*)d_in[20];
    const float* Wtk = (const float*)d_in[21]; const float* btk = (const float*)d_in[22];
    const float* Wtv = (const float*)d_in[23]; const float* btv = (const float*)d_in[24];
    const float* lnpg= (const float*)d_in[25]; const float* lnpb= (const float*)d_in[26];
    const float* Wl1 = (const float*)d_in[27]; const float* bl1 = (const float*)d_in[28];
    const float* Wl2 = (const float*)d_in[29]; const float* bl2 = (const float*)d_in[30];
    const float* Wsp = (const float*)d_in[31]; const float* bsp = (const float*)d_in[32];

    char* ws = (char*)d_ws;
    size_t off = 0;
    auto alloc = [&](size_t bytes) -> char* {
        off = (off + 255) & ~(size_t)255;
        char* p = ws + off;
        off += bytes;
        return p;
    };
    const size_t T = 4096, TS = 131072;
    const size_t MB8 = T * 1024 * 2, MB16 = T * 2048 * 2;
    bf16t* R_xn   = (bf16t*)alloc(MB8);    // xn -> hbuf
    bf16t* R_h1   = (bf16t*)alloc(MB8);    // qf
    bf16t* R_kv0  = (bf16t*)alloc(MB16);   // kv0
    bf16t* R_inp  = (bf16t*)alloc(MB16);   // inp -> attn_out
    bf16t* R_kk   = (bf16t*)alloc(MB16);   // kk -> slotsO
    bf16t* R_vv   = (bf16t*)alloc(MB16);   // vvT -> res (fp32, 16MB)
    bf16t* R_sl   = (bf16t*)alloc(MB16);   // slots(final) -> r1
    bf16t* Wcat   = (bf16t*)alloc(5120 * 1024 * 2); // concat proj weights; later rotates Wf/Wr1/Wr2
    bf16t* WtkT = (bf16t*)alloc(64 * 64 * 2);
    bf16t* WtvT = (bf16t*)alloc(64 * 64 * 2);
    bf16t* WtqI = (bf16t*)alloc(64 * 128 * 2);
    bf16t* Wl1T = (bf16t*)alloc(128 * 64 * 2);
    bf16t* Wl2T = (bf16t*)alloc(64 * 128 * 2);
    bf16t* WspT = (bf16t*)alloc(64 * 128 * 2);
    float* bcat = (float*)alloc(5120 * 4);
    float* Kmat = (float*)alloc(64 * 4096 * 4);
    float* ksum = (float*)alloc(64 * 64 * 4);

    if (off > ws_size) {
        fill_k<<<(out_size + 255) / 256, 256, 0, stream>>>((float*)d_out, out_size, 1000.f);
        return;
    }
    float* R_res = (float*)R_vv;   // fp32 res overlays vvT after slot phase

    auto tr = [&](const float* W, bf16t* Wt, int R, int C) {
        dim3 g((C + 31) / 32, (R + 31) / 32), blk(32, 8);
        transpose_k<<<g, blk, 0, stream>>>(W, Wt, R, C);
    };

    small_prep_k<<<7, 256, 0, stream>>>(Wtk, Wtv, Wtq, Wl1, Wl2, Wsp, bk, bv, bip, bq,
                                        WtkT, WtvT, WtqI, Wl1T, Wl2T, WspT, bcat);

    // LN1 (fp32 x -> bf16 xn)
    ln_kernel<<<4096, 256, 0, stream>>>(x, ln1g, ln1b, R_xn);

    // concat weight transposes: rows [Wk | Wv | Wip | Wq]
    tr(Wk, Wcat, 1024, 1024);
    tr(Wv, Wcat + (size_t)1024 * 1024, 1024, 1024);
    tr(Wip, Wcat + (size_t)2048 * 1024, 1024, 2048);
    tr(Wq, Wcat + (size_t)4096 * 1024, 1024, 1024);

    // merged projection: kv0, inp, qf in one launch (1280 blocks)
    gemm_proj_k<<<1280, 256, 0, stream>>>(R_xn, Wcat, bcat, R_kv0, R_inp, R_h1);

    // kk = feat(inp@WtkT+btk); vvT = (inp@WtvT+btv) stored [t][e][w]
    LAUNCH_GEMM(1, bf16t, R_inp, WtkT, btk, R_kk, 131072, 64, 64, 64);
    LAUNCH_GEMM(7, bf16t, R_inp, WtvT, btv, R_vv, 131072, 64, 64, 64);

    // fused slot loop (3 iterations), two waves per token
    slot_all_k<<<2048, 256, 0, stream>>>(R_kv0, R_kk, R_vv, WtqI, btq, lnpg, lnpb,
                                         Wl1T, bl1, Wl2T, bl2, R_sl);

    // slotsO = [kv0|slots]@Wsp + bsp -> R_kk (kk dead)
    gemm_cat_k<<<512, 256, 0, stream>>>(R_kv0, R_sl, WspT, bsp, R_kk, 131072);

    // linear attention: Kmat/ksum via MFMA, no atomics
    kv_outer_k<<<64, 256, 0, stream>>>(R_kk, Kmat, ksum);

    // attn_out -> R_inp (inp dead)
    attn_out_k<<<4096, 256, 0, stream>>>(R_h1, Kmat, ksum, R_inp);

    // res = x + attn_out@Wf + bf -> fp32 R_res (vvT dead); Wcat reused as rotate buffer
    tr(Wf, Wcat, 1024, 1024);
    LAUNCH_GEMM128(5, float, float, R_inp, Wcat, bWf, x, R_res, 4096, 1024, 1024, 1024);

    // final MLP with residual
    ln_kernel<<<4096, 256, 0, stream>>>(R_res, ln2g, ln2b, R_xn);   // hbuf (xn dead)
    tr(Wr1, Wcat, 1024, 2048);
    LAUNCH_GEMM128(4, bf16t, bf16t, R_xn, Wcat, br1, nullptr, R_sl, 4096, 2048, 1024, 2048);
    tr(Wr2, Wcat, 2048, 1024);
    LAUNCH_GEMM128(5, float, float, R_sl, Wcat, br2, R_res, (float*)d_out, 4096, 1024, 2048, 1024);
}

// Round 10
// 573.223 us; speedup vs baseline: 1.1377x; 1.1377x over previous
//
#include <hip/hip_runtime.h>
#include <hip/hip_bf16.h>

typedef __hip_bfloat16 bf16t;
typedef short short8 __attribute__((ext_vector_type(8)));
typedef float f32x4 __attribute__((ext_vector_type(4)));

// B=4, S=1024, D=1024, H=16, E=64, N=32 slots; tokens T=4096; slot-rows TS=131072
// Inputs/outputs are FLOAT32 (per reference). Internal activations bf16 for MFMA.

__device__ __forceinline__ float featf(float x) { return x > 0.f ? x + 1.f : expf(x); }
__device__ __forceinline__ float ldf(const bf16t* p, size_t i) { return __bfloat162float(p[i]); }
__device__ __forceinline__ float ldf(const float* p, size_t i) { return p[i]; }
__device__ __forceinline__ void stf(bf16t* p, size_t i, float v) { p[i] = __float2bfloat16(v); }
__device__ __forceinline__ void stf(float* p, size_t i, float v) { p[i] = v; }
__device__ __forceinline__ float b2f(unsigned short u) {
    unsigned int x = ((unsigned int)u) << 16; float f; __builtin_memcpy(&f, &x, 4); return f;
}
__device__ __forceinline__ unsigned short f2b(float f) {
    bf16t h = __float2bfloat16(f); unsigned short u; __builtin_memcpy(&u, &h, 2); return u;
}
// async global->LDS, 16B per lane; lds dest = wave-uniform base + lane*16
__device__ __forceinline__ void gl_lds16(const short* g, short* l) {
    __builtin_amdgcn_global_load_lds((const __attribute__((address_space(1))) unsigned int*)g,
                                     (__attribute__((address_space(3))) unsigned int*)l, 16, 0, 0);
}
#define MFMA16(a, b, c) __builtin_amdgcn_mfma_f32_16x16x32_bf16((a), (b), (c), 0, 0, 0)

// ---------------- sentinel fill (ws too small diagnostic) ----------------
__global__ __launch_bounds__(256) void fill_k(float* __restrict__ out, int n, float v) {
    int i = blockIdx.x * 256 + threadIdx.x;
    if (i < n) out[i] = v;
}

// ---------------- merged 4-job transpose + fp32->bf16 convert ----------------
__global__ __launch_bounds__(256) void multi_transpose_k(const float* __restrict__ s0, const float* __restrict__ s1,
                                                         const float* __restrict__ s2, const float* __restrict__ s3,
                                                         bf16t* __restrict__ d0, bf16t* __restrict__ d1,
                                                         bf16t* __restrict__ d2, bf16t* __restrict__ d3,
                                                         int R0, int C0, int R1, int C1, int R2, int C2, int R3, int C3,
                                                         int e0, int e1, int e2) {
    __shared__ bf16t tile[32][33];
    int b = blockIdx.x;
    const float* W; bf16t* Wt; int C, R, lb;
    if (b < e0)      { W = s0; Wt = d0; R = R0; C = C0; lb = b; }
    else if (b < e1) { W = s1; Wt = d1; R = R1; C = C1; lb = b - e0; }
    else if (b < e2) { W = s2; Wt = d2; R = R2; C = C2; lb = b - e1; }
    else             { W = s3; Wt = d3; R = R3; C = C3; lb = b - e2; }
    int tiles_c = C >> 5;
    int c0 = (lb % tiles_c) * 32, r0 = (lb / tiles_c) * 32;
    int tx = threadIdx.x & 31, ty = threadIdx.x >> 5;  // 32 x 8
    #pragma unroll
    for (int i = 0; i < 32; i += 8)
        tile[ty + i][tx] = __float2bfloat16(W[(size_t)(r0 + ty + i) * C + (c0 + tx)]);
    __syncthreads();
    #pragma unroll
    for (int i = 0; i < 32; i += 8)
        Wt[(size_t)(c0 + ty + i) * R + (r0 + tx)] = tile[tx][ty + i];
}

// ---------------- fused small-weight prep (transposes + WtqI + WtkvT + bias concats) --------
__global__ __launch_bounds__(256) void small_prep_k(const float* __restrict__ Wtk,
                                                    const float* __restrict__ Wtv,
                                                    const float* __restrict__ Wtq,
                                                    const float* __restrict__ Wl1,
                                                    const float* __restrict__ Wl2,
                                                    const float* __restrict__ Wsp,
                                                    const float* __restrict__ bk,
                                                    const float* __restrict__ bv,
                                                    const float* __restrict__ bip,
                                                    const float* __restrict__ bq,
                                                    const float* __restrict__ btk,
                                                    const float* __restrict__ btv,
                                                    bf16t* __restrict__ WtkvT,
                                                    bf16t* __restrict__ WtqI,
                                                    bf16t* __restrict__ Wl1T,
                                                    bf16t* __restrict__ Wl2T,
                                                    bf16t* __restrict__ WspT,
                                                    float* __restrict__ bcat,
                                                    float* __restrict__ bcat2) {
    int b = blockIdx.x, tid = threadIdx.x;
    if (b == 0) {
        for (int i = tid; i < 8192; i += 256) {
            int n2 = i >> 6, e = i & 63;
            float v = (n2 < 64) ? Wtk[e * 64 + n2] : Wtv[e * 64 + (n2 - 64)];
            WtkvT[i] = __float2bfloat16(v);
        }
    } else if (b == 1) {
        for (int i = tid; i < 8192; i += 256) {
            int e = i >> 7, k = i & 127;
            float v = (k < 64) ? Wtq[k * 64 + e] : ((k - 64 == e) ? 1.f : 0.f);
            WtqI[i] = __float2bfloat16(v);
        }
    } else if (b == 2) {
        for (int i = tid; i < 8192; i += 256) { int n = i >> 6, k = i & 63; Wl1T[i] = __float2bfloat16(Wl1[k * 128 + n]); }
    } else if (b == 3) {
        for (int i = tid; i < 8192; i += 256) { int n = i >> 7, k = i & 127; Wl2T[i] = __float2bfloat16(Wl2[k * 64 + n]); }
    } else if (b == 4) {
        for (int i = tid; i < 8192; i += 256) { int n = i >> 7, k = i & 127; WspT[i] = __float2bfloat16(Wsp[k * 64 + n]); }
    } else if (b == 5) {
        for (int i = tid; i < 5120; i += 256) {
            float v;
            if (i < 1024) v = bk[i];
            else if (i < 2048) v = bv[i - 1024];
            else if (i < 4096) v = bip[i - 2048];
            else v = bq[i - 4096];
            bcat[i] = v;
        }
    } else {
        if (tid < 128) bcat2[tid] = (tid < 64) ? btk[tid] : btv[tid - 64];
    }
}

// ---------------- LayerNorm over D=1024 (fp32 in, bf16 out), one block/token ----------------
__global__ __launch_bounds__(256) void ln_kernel(const float* __restrict__ X,
                                                 const float* __restrict__ g,
                                                 const float* __restrict__ b,
                                                 bf16t* __restrict__ Y) {
    int t = blockIdx.x, tid = threadIdx.x;
    size_t base = (size_t)t * 1024 + tid * 4;
    float v0 = X[base + 0], v1 = X[base + 1], v2 = X[base + 2], v3 = X[base + 3];
    float s = v0 + v1 + v2 + v3;
    float q = v0 * v0 + v1 * v1 + v2 * v2 + v3 * v3;
    __shared__ float rs[4], rq[4];
    for (int o = 32; o > 0; o >>= 1) { s += __shfl_down(s, o); q += __shfl_down(q, o); }
    int wid = tid >> 6, lane = tid & 63;
    if (lane == 0) { rs[wid] = s; rq[wid] = q; }
    __syncthreads();
    float S = rs[0] + rs[1] + rs[2] + rs[3];
    float Q = rq[0] + rq[1] + rq[2] + rq[3];
    float mean = S * (1.f / 1024.f);
    float var = Q * (1.f / 1024.f) - mean * mean;
    float rstd = rsqrtf(var + 1e-5f);
    int c = tid * 4;
    stf(Y, base + 0, (v0 - mean) * rstd * g[c + 0] + b[c + 0]);
    stf(Y, base + 1, (v1 - mean) * rstd * g[c + 1] + b[c + 1]);
    stf(Y, base + 2, (v2 - mean) * rstd * g[c + 2] + b[c + 2]);
    stf(Y, base + 3, (v3 - mean) * rstd * g[c + 3] + b[c + 3]);
}

// ======= 128x128-tile MFMA GEMM (m97 pattern): C = A[M,K] @ Bt[N,K]^T + bias, epilogues =====
// MODE 0: v   4: relu(v)   5: v+add
template <int MODE, typename TC, typename TADD>
__global__ __launch_bounds__(256) void gemm128_k(const bf16t* __restrict__ A,
                                                 const bf16t* __restrict__ Bt,
                                                 const float* __restrict__ bias,
                                                 const TADD* __restrict__ add,
                                                 TC* __restrict__ C,
                                                 int M, int N, int K, int ldC) {
    __shared__ short As[128 * 32];
    __shared__ short Bs[128 * 32];
    int tid = threadIdx.x;
    int wave = tid >> 6, lane = tid & 63;
    int l16 = lane & 15, quad = lane >> 4;
    int tilesM = M >> 7;
    int tm = blockIdx.x % tilesM;           // column-major: consecutive blocks share B tile
    int tn = blockIdx.x / tilesM;
    int wm = wave >> 1, wn = wave & 1;

    int lrow = lane >> 2;
    int lseg = (lane & 3) * 8;
    const short* Ag = (const short*)A + (size_t)(tm * 128 + wave * 32 + lrow) * K + lseg;
    const short* Ag2 = Ag + (size_t)16 * K;
    const short* Bg = (const short*)Bt + (size_t)(tn * 128 + wave * 32 + lrow) * K + lseg;
    const short* Bg2 = Bg + (size_t)16 * K;
    short* Asw = As + (wave * 32) * 32;
    short* Asw2 = Asw + 16 * 32;
    short* Bsw = Bs + (wave * 32) * 32;
    short* Bsw2 = Bsw + 16 * 32;

    f32x4 acc[4][4] = {};
    for (int k0 = 0; k0 < K; k0 += 32) {
        gl_lds16(Ag + k0, Asw);
        gl_lds16(Ag2 + k0, Asw2);
        gl_lds16(Bg + k0, Bsw);
        gl_lds16(Bg2 + k0, Bsw2);
        __syncthreads();
        short8 av[4], bv[4];
        #pragma unroll
        for (int i = 0; i < 4; i++)
            av[i] = *(const short8*)(As + (wm * 64 + i * 16 + l16) * 32 + quad * 8);
        #pragma unroll
        for (int j = 0; j < 4; j++)
            bv[j] = *(const short8*)(Bs + (wn * 64 + j * 16 + l16) * 32 + quad * 8);
        #pragma unroll
        for (int i = 0; i < 4; i++)
            #pragma unroll
            for (int j = 0; j < 4; j++)
                acc[i][j] = MFMA16(av[i], bv[j], acc[i][j]);
        __syncthreads();
    }

    #pragma unroll
    for (int j = 0; j < 4; j++) {
        int col = tn * 128 + wn * 64 + j * 16 + l16;
        float bcol = bias[col];
        #pragma unroll
        for (int i = 0; i < 4; i++) {
            int row0 = tm * 128 + wm * 64 + i * 16 + quad * 4;
            #pragma unroll
            for (int r = 0; r < 4; r++) {
                int row = row0 + r;
                float v = acc[i][j][r] + bcol;
                float outv;
                if constexpr (MODE == 0) outv = v;
                else if constexpr (MODE == 4) outv = fmaxf(v, 0.f);
                else if constexpr (MODE == 5) outv = v + ldf(add, (size_t)row * N + col);
                else outv = v;
                stf(C, (size_t)row * ldC + col, outv);
            }
        }
    }
}

// ======= merged projection GEMM: [xn] @ [Wk|Wv|Wip|Wq]^T (N=5120), split epilogue =========
__global__ __launch_bounds__(256) void gemm_proj_k(const bf16t* __restrict__ A,
                                                   const bf16t* __restrict__ Bt,
                                                   const float* __restrict__ bias,
                                                   bf16t* __restrict__ kv0,
                                                   bf16t* __restrict__ inp,
                                                   bf16t* __restrict__ qf) {
    __shared__ short As[128 * 32];
    __shared__ short Bs[128 * 32];
    const int K = 1024;
    int tid = threadIdx.x;
    int wave = tid >> 6, lane = tid & 63;
    int l16 = lane & 15, quad = lane >> 4;
    int tm = blockIdx.x & 31;
    int tn = blockIdx.x >> 5;
    int wm = wave >> 1, wn = wave & 1;

    int lrow = lane >> 2;
    int lseg = (lane & 3) * 8;
    const short* Ag = (const short*)A + (size_t)(tm * 128 + wave * 32 + lrow) * K + lseg;
    const short* Ag2 = Ag + (size_t)16 * K;
    const short* Bg = (const short*)Bt + (size_t)(tn * 128 + wave * 32 + lrow) * K + lseg;
    const short* Bg2 = Bg + (size_t)16 * K;
    short* Asw = As + (wave * 32) * 32;
    short* Asw2 = Asw + 16 * 32;
    short* Bsw = Bs + (wave * 32) * 32;
    short* Bsw2 = Bsw + 16 * 32;

    f32x4 acc[4][4] = {};
    for (int k0 = 0; k0 < K; k0 += 32) {
        gl_lds16(Ag + k0, Asw);
        gl_lds16(Ag2 + k0, Asw2);
        gl_lds16(Bg + k0, Bsw);
        gl_lds16(Bg2 + k0, Bsw2);
        __syncthreads();
        short8 av[4], bv[4];
        #pragma unroll
        for (int i = 0; i < 4; i++)
            av[i] = *(const short8*)(As + (wm * 64 + i * 16 + l16) * 32 + quad * 8);
        #pragma unroll
        for (int j = 0; j < 4; j++)
            bv[j] = *(const short8*)(Bs + (wn * 64 + j * 16 + l16) * 32 + quad * 8);
        #pragma unroll
        for (int i = 0; i < 4; i++)
            #pragma unroll
            for (int j = 0; j < 4; j++)
                acc[i][j] = MFMA16(av[i], bv[j], acc[i][j]);
        __syncthreads();
    }

    #pragma unroll
    for (int j = 0; j < 4; j++) {
        int col = tn * 128 + wn * 64 + j * 16 + l16;
        float bcol = bias[col];
        #pragma unroll
        for (int i = 0; i < 4; i++) {
            int row0 = tm * 128 + wm * 64 + i * 16 + quad * 4;
            #pragma unroll
            for (int r = 0; r < 4; r++) {
                int row = row0 + r;
                float v = acc[i][j][r] + bcol;
                if (tn < 16) stf(kv0, (size_t)row * 2048 + col, v);
                else if (tn < 32) stf(inp, (size_t)row * 2048 + (col - 2048), v);
                else stf(qf, (size_t)row * 1024 + (col - 4096), featf(v * 0.125f));
            }
        }
    }
}

// ------- merged kk/vvT GEMM: inp[TS,64] @ [WtkT|WtvT]^T; kk=feat, vvT transpose-store -------
__global__ __launch_bounds__(256) void gemm_kv_k(const bf16t* __restrict__ A,
                                                 const bf16t* __restrict__ Bt,
                                                 const float* __restrict__ bias,
                                                 bf16t* __restrict__ kkO,
                                                 bf16t* __restrict__ vvTO) {
    int wave = threadIdx.x >> 6, lane = threadIdx.x & 63;
    int tile = blockIdx.x * 4 + wave;        // 4096 tiles: 2048 m x 2 n
    int tm = tile >> 1, tn = tile & 1;
    int l16 = lane & 15, quad = lane >> 4;
    f32x4 acc[4][4] = {};
    const short* Ab = (const short*)A + (size_t)(tm * 64 + l16) * 64;
    const short* Bb = (const short*)Bt + (size_t)(tn * 64 + l16) * 64;
    #pragma unroll
    for (int k0 = 0; k0 < 64; k0 += 32) {
        int ka = k0 + quad * 8;
        short8 av[4], bv[4];
        #pragma unroll
        for (int i = 0; i < 4; i++) av[i] = *(const short8*)(Ab + (size_t)i * 16 * 64 + ka);
        #pragma unroll
        for (int j = 0; j < 4; j++) bv[j] = *(const short8*)(Bb + (size_t)j * 16 * 64 + ka);
        #pragma unroll
        for (int i = 0; i < 4; i++)
            #pragma unroll
            for (int j = 0; j < 4; j++)
                acc[i][j] = MFMA16(av[i], bv[j], acc[i][j]);
    }
    #pragma unroll
    for (int j = 0; j < 4; j++) {
        int col = j * 16 + l16;
        float bcol = bias[tn * 64 + col];
        #pragma unroll
        for (int i = 0; i < 4; i++) {
            int row0 = tm * 64 + i * 16 + quad * 4;
            #pragma unroll
            for (int r = 0; r < 4; r++) {
                int row = row0 + r;
                float v = acc[i][j][r] + bcol;
                if (tn == 0) kkO[(size_t)row * 64 + col] = __float2bfloat16(featf(v));
                else stf(vvTO, (size_t)(row >> 5) * 2048 + (size_t)col * 32 + (row & 31), v);
            }
        }
    }
}

// ---------------- fused concat GEMM: C[TS,64] = [A1|A2] @ Bt[64,128]^T + bias -------------
__global__ __launch_bounds__(256) void gemm_cat_k(const bf16t* __restrict__ A1,
                                                  const bf16t* __restrict__ A2,
                                                  const bf16t* __restrict__ Bt,
                                                  const float* __restrict__ bias,
                                                  bf16t* __restrict__ C, int M) {
    int wave = threadIdx.x >> 6;
    int lane = threadIdx.x & 63;
    int tiles = M >> 6;
    int tile = blockIdx.x * 4 + wave;
    if (tile >= tiles) return;
    int tm = tile;
    int l16 = lane & 15, quad = lane >> 4;
    f32x4 acc[4][4] = {};
    #pragma unroll
    for (int p = 0; p < 2; p++) {
        const short* Ab = (const short*)(p ? A2 : A1) + (size_t)(tm * 64 + l16) * 64;
        const short* Bb = (const short*)Bt + (size_t)l16 * 128 + p * 64;
        #pragma unroll
        for (int k0 = 0; k0 < 64; k0 += 32) {
            int ka = k0 + quad * 8;
            short8 av[4], bv[4];
            #pragma unroll
            for (int i = 0; i < 4; i++) av[i] = *(const short8*)(Ab + (size_t)i * 16 * 64 + ka);
            #pragma unroll
            for (int j = 0; j < 4; j++) bv[j] = *(const short8*)(Bb + (size_t)j * 16 * 128 + ka);
            #pragma unroll
            for (int i = 0; i < 4; i++)
                #pragma unroll
                for (int j = 0; j < 4; j++)
                    acc[i][j] = MFMA16(av[i], bv[j], acc[i][j]);
        }
    }
    #pragma unroll
    for (int j = 0; j < 4; j++) {
        int col = j * 16 + l16;
        float bcol = bias[col];
        #pragma unroll
        for (int i = 0; i < 4; i++) {
            int row0 = tm * 64 + i * 16 + quad * 4;
            #pragma unroll
            for (int r = 0; r < 4; r++)
                C[(size_t)(row0 + r) * 64 + col] = __float2bfloat16(acc[i][j][r] + bcol);
        }
    }
}

// ========== fused slot loop: all 3 iterations, one wave per token, MFMA throughout =========
// Register diet: NOTHING cached across iterations except S/X pointers; all fragment/bias
// loads are re-issued per iteration with a runtime-zero offset (zoff) to defeat LICM.
__global__ __launch_bounds__(256) void slot_all_k(const bf16t* __restrict__ kv0,
                                                  const bf16t* __restrict__ kk,
                                                  const bf16t* __restrict__ vvT,
                                                  const bf16t* __restrict__ WtqI,
                                                  const float* __restrict__ btq,
                                                  const float* __restrict__ lnpg,
                                                  const float* __restrict__ lnpb,
                                                  const bf16t* __restrict__ Wl1T,
                                                  const float* __restrict__ bl1,
                                                  const bf16t* __restrict__ Wl2T,
                                                  const float* __restrict__ bl2,
                                                  bf16t* __restrict__ slots_out,
                                                  int zoff) {
    __shared__ short slotsS[4][32 * 72];   // per-wave slots [n][e] pitch 72
    __shared__ short scratch[4][32 * 72];  // per-wave qq/attnT/hln/h1-chunk
    int wave = threadIdx.x >> 6, lane = threadIdx.x & 63;
    int l16 = lane & 15, quad = lane >> 4;
    int t = blockIdx.x * 4 + wave;
    short* S = slotsS[wave];
    short* X = scratch[wave];
    size_t tbase = (size_t)t * 2048;

    // slots := kv0 (vectorized copy to LDS, pitch 72)
    {
        const short* src = (const short*)kv0 + tbase;
        #pragma unroll
        for (int p = 0; p < 4; p++) {
            int idx = p * 512 + lane * 8;
            int row = idx >> 6, col = idx & 63;
            *(short8*)(S + row * 72 + col) = *(const short8*)(src + idx);
        }
    }

    #pragma unroll 1
    for (int it = 0; it < 3; it++) {
        int vo = it * zoff;   // zoff==0 at runtime; symbolic per-iteration offset
        // ---- qq = feat(([slots|kv0] @ WtqI^T + btq)/8) -> X [n][e] pitch 72
        f32x4 aq[2][4] = {};
        #pragma unroll
        for (int k0 = 0; k0 < 4; k0++) {
            short8 af[2];
            #pragma unroll
            for (int i = 0; i < 2; i++) {
                if (k0 < 2)
                    af[i] = *(const short8*)(S + (i * 16 + l16) * 72 + k0 * 32 + quad * 8);
                else
                    af[i] = *(const short8*)((const short*)kv0 + tbase + (size_t)((i * 16 + l16) * 64 + (k0 - 2) * 32 + quad * 8 + vo));
            }
            #pragma unroll
            for (int j = 0; j < 4; j++) {
                short8 bf_ = *(const short8*)((const short*)WtqI + (size_t)((j * 16 + l16) * 128 + k0 * 32 + quad * 8 + vo));
                #pragma unroll
                for (int i = 0; i < 2; i++) aq[i][j] = MFMA16(af[i], bf_, aq[i][j]);
            }
        }
        {
            float btqv[4];
            #pragma unroll
            for (int j = 0; j < 4; j++) btqv[j] = btq[j * 16 + l16 + vo];
            #pragma unroll
            for (int i = 0; i < 2; i++)
                #pragma unroll
                for (int j = 0; j < 4; j++)
                    #pragma unroll
                    for (int r = 0; r < 4; r++) {
                        int n = i * 16 + quad * 4 + r, e = j * 16 + l16;
                        X[n * 72 + e] = (short)f2b(featf((aq[i][j][r] + btqv[j]) * 0.125f));
                    }
        }
        // ---- logits[w][n] = kk @ qq^T
        f32x4 al[2][2] = {};
        #pragma unroll
        for (int k0 = 0; k0 < 2; k0++) {
            short8 ak[2], bf_[2];
            #pragma unroll
            for (int i = 0; i < 2; i++)
                ak[i] = *(const short8*)((const short*)kk + tbase + (size_t)((i * 16 + l16) * 64 + k0 * 32 + quad * 8 + vo));
            #pragma unroll
            for (int j = 0; j < 2; j++)
                bf_[j] = *(const short8*)(X + (j * 16 + l16) * 72 + k0 * 32 + quad * 8);
            #pragma unroll
            for (int i = 0; i < 2; i++)
                #pragma unroll
                for (int j = 0; j < 2; j++)
                    al[i][j] = MFMA16(ak[i], bf_[j], al[i][j]);
        }
        // ---- softmax over n (rows w), normalize over w (cols n)
        #pragma unroll
        for (int i = 0; i < 2; i++)
            #pragma unroll
            for (int r = 0; r < 4; r++) {
                float m = fmaxf(al[i][0][r], al[i][1][r]);
                #pragma unroll
                for (int d = 1; d < 16; d <<= 1) m = fmaxf(m, __shfl_xor(m, d));
                float e0 = expf(al[i][0][r] - m), e1 = expf(al[i][1][r] - m);
                float s = e0 + e1;
                #pragma unroll
                for (int d = 1; d < 16; d <<= 1) s += __shfl_xor(s, d);
                float inv = 1.f / s;
                al[i][0][r] = e0 * inv + 1e-6f;
                al[i][1][r] = e1 * inv + 1e-6f;
            }
        #pragma unroll
        for (int j = 0; j < 2; j++) {
            float cs = 0.f;
            #pragma unroll
            for (int i = 0; i < 2; i++)
                #pragma unroll
                for (int r = 0; r < 4; r++) cs += al[i][j][r];
            cs += __shfl_xor(cs, 16);
            cs += __shfl_xor(cs, 32);
            float inv = 1.f / cs;
            #pragma unroll
            for (int i = 0; i < 2; i++)
                #pragma unroll
                for (int r = 0; r < 4; r++) al[i][j][r] *= inv;
        }
        // ---- attn^T -> X [n][w] pitch 40
        #pragma unroll
        for (int i = 0; i < 2; i++)
            #pragma unroll
            for (int j = 0; j < 2; j++)
                #pragma unroll
                for (int r = 0; r < 4; r++) {
                    int w = i * 16 + quad * 4 + r, n = j * 16 + l16;
                    X[n * 40 + w] = (short)f2b(al[i][j][r]);
                }
        // ---- upd[n][e] = attnT @ vvT
        f32x4 au[2][4] = {};
        {
            short8 af[2];
            #pragma unroll
            for (int i = 0; i < 2; i++)
                af[i] = *(const short8*)(X + (i * 16 + l16) * 40 + quad * 8);
            #pragma unroll
            for (int j = 0; j < 4; j++) {
                short8 bf_ = *(const short8*)((const short*)vvT + tbase + (size_t)((j * 16 + l16) * 32 + quad * 8 + vo));
                #pragma unroll
                for (int i = 0; i < 2; i++) au[i][j] = MFMA16(af[i], bf_, au[i][j]);
            }
        }
        // ---- LN over e per row n -> X [n][e] pitch 72
        {
            float lgv[4], lbv[4];
            #pragma unroll
            for (int j = 0; j < 4; j++) { lgv[j] = lnpg[j * 16 + l16 + vo]; lbv[j] = lnpb[j * 16 + l16 + vo]; }
            #pragma unroll
            for (int i = 0; i < 2; i++)
                #pragma unroll
                for (int r = 0; r < 4; r++) {
                    float s1 = 0.f, s2 = 0.f;
                    #pragma unroll
                    for (int j = 0; j < 4; j++) { float u = au[i][j][r]; s1 += u; s2 += u * u; }
                    #pragma unroll
                    for (int d = 1; d < 16; d <<= 1) { s1 += __shfl_xor(s1, d); s2 += __shfl_xor(s2, d); }
                    float mean = s1 * (1.f / 64.f);
                    float var = s2 * (1.f / 64.f) - mean * mean;
                    float rstd = rsqrtf(var + 1e-5f);
                    int n = i * 16 + quad * 4 + r;
                    #pragma unroll
                    for (int j = 0; j < 4; j++)
                        X[n * 72 + j * 16 + l16] = (short)f2b((au[i][j][r] - mean) * rstd * lgv[j] + lbv[j]);
                }
        }
        // ---- MLP (chunked): preload hln A-frags, then 2 chunks of 64 h1-cols
        short8 a1[2][2];
        #pragma unroll
        for (int i = 0; i < 2; i++)
            #pragma unroll
            for (int k0 = 0; k0 < 2; k0++)
                a1[i][k0] = *(const short8*)(X + (i * 16 + l16) * 72 + k0 * 32 + quad * 8);
        f32x4 ac2[2][4] = {};
        #pragma unroll
        for (int c = 0; c < 2; c++) {
            f32x4 ac1[2][4] = {};
            #pragma unroll
            for (int k0 = 0; k0 < 2; k0++)
                #pragma unroll
                for (int j = 0; j < 4; j++) {
                    short8 bf_ = *(const short8*)((const short*)Wl1T + (size_t)(((c * 4 + j) * 16 + l16) * 64 + k0 * 32 + quad * 8 + vo));
                    #pragma unroll
                    for (int i = 0; i < 2; i++) ac1[i][j] = MFMA16(a1[i][k0], bf_, ac1[i][j]);
                }
            {
                float bl1v[4];
                #pragma unroll
                for (int j = 0; j < 4; j++) bl1v[j] = bl1[(c * 4 + j) * 16 + l16 + vo];
                #pragma unroll
                for (int i = 0; i < 2; i++)
                    #pragma unroll
                    for (int j = 0; j < 4; j++)
                        #pragma unroll
                        for (int r = 0; r < 4; r++) {
                            int n = i * 16 + quad * 4 + r;
                            X[n * 72 + j * 16 + l16] = (short)f2b(fmaxf(ac1[i][j][r] + bl1v[j], 0.f));
                        }
            }
            #pragma unroll
            for (int kc = 0; kc < 2; kc++) {
                short8 a2[2];
                #pragma unroll
                for (int i = 0; i < 2; i++)
                    a2[i] = *(const short8*)(X + (i * 16 + l16) * 72 + kc * 32 + quad * 8);
                int k1 = c * 2 + kc;
                #pragma unroll
                for (int j = 0; j < 4; j++) {
                    short8 bf_ = *(const short8*)((const short*)Wl2T + (size_t)((j * 16 + l16) * 128 + k1 * 32 + quad * 8 + vo));
                    #pragma unroll
                    for (int i = 0; i < 2; i++) ac2[i][j] = MFMA16(a2[i], bf_, ac2[i][j]);
                }
            }
        }
        // ---- slot update
        {
            float bl2v[4];
            #pragma unroll
            for (int j = 0; j < 4; j++) bl2v[j] = bl2[j * 16 + l16 + vo];
            #pragma unroll
            for (int i = 0; i < 2; i++)
                #pragma unroll
                for (int j = 0; j < 4; j++)
                    #pragma unroll
                    for (int r = 0; r < 4; r++) {
                        int n = i * 16 + quad * 4 + r, e = j * 16 + l16;
                        float old = b2f((unsigned short)S[n * 72 + e]);
                        S[n * 72 + e] = (short)f2b(old + (ac2[i][j][r] + bl2v[j]) * (1.f / 64.f));
                    }
        }
    }
    // write final slots
    {
        short* dst = (short*)slots_out + tbase;
        #pragma unroll
        for (int p = 0; p < 4; p++) {
            int idx = p * 512 + lane * 8;
            int row = idx >> 6, col = idx & 63;
            *(short8*)(dst + idx) = *(const short8*)(S + row * 72 + col);
        }
    }
}

// ---------------- Kmat[bh] = kf^T @ v2 over s (MFMA, no atomics); ksum[bh] = sum_s kf ------
__global__ __launch_bounds__(256) void kv_outer_k(const bf16t* __restrict__ slotsO,
                                                  float* __restrict__ Kmat,
                                                  float* __restrict__ ksum) {
    __shared__ short kfT[64 * 72];   // [e][s] pitch 72
    __shared__ short v2T[64 * 72];
    __shared__ float ksred[8][64];
    int bh = blockIdx.x;
    int b = bh >> 4, h = bh & 15;
    int tid = threadIdx.x;
    int wave = tid >> 6, lane = tid & 63;
    int l16 = lane & 15, quad = lane >> 4;
    int m0 = wave * 16;

    int sgrp = tid >> 5;
    int e0 = (tid & 31) * 2;
    float ks0 = 0.f, ks1 = 0.f;
    f32x4 acc[4];
    #pragma unroll
    for (int j = 0; j < 4; j++) acc[j] = (f32x4){0.f, 0.f, 0.f, 0.f};

    for (int tile = 0; tile < 16; tile++) {
        #pragma unroll
        for (int p = 0; p < 8; p++) {
            int sl = p * 8 + sgrp;
            size_t row = ((size_t)(b * 1024 + tile * 64 + sl)) * 2048;
            unsigned int dk = *(const unsigned int*)((const unsigned short*)slotsO + row + h * 64 + e0);
            float f0 = featf(b2f((unsigned short)(dk & 0xffff)));
            float f1 = featf(b2f((unsigned short)(dk >> 16)));
            ks0 += f0; ks1 += f1;
            kfT[e0 * 72 + sl] = (short)f2b(f0);
            kfT[(e0 + 1) * 72 + sl] = (short)f2b(f1);
            unsigned int dv = *(const unsigned int*)((const unsigned short*)slotsO + row + (16 + h) * 64 + e0);
            v2T[e0 * 72 + sl] = (short)(dv & 0xffff);
            v2T[(e0 + 1) * 72 + sl] = (short)(dv >> 16);
        }
        __syncthreads();
        #pragma unroll
        for (int k2 = 0; k2 < 2; k2++) {
            short8 a = *(const short8*)(kfT + (m0 + l16) * 72 + k2 * 32 + quad * 8);
            #pragma unroll
            for (int j = 0; j < 4; j++) {
                short8 bv = *(const short8*)(v2T + (j * 16 + l16) * 72 + k2 * 32 + quad * 8);
                acc[j] = MFMA16(a, bv, acc[j]);
            }
        }
        __syncthreads();
    }

    float* Km = Kmat + (size_t)bh * 4096;
    #pragma unroll
    for (int j = 0; j < 4; j++)
        #pragma unroll
        for (int r = 0; r < 4; r++)
            Km[(m0 + quad * 4 + r) * 64 + j * 16 + l16] = acc[j][r];

    ksred[sgrp][e0] = ks0;
    ksred[sgrp][e0 + 1] = ks1;
    __syncthreads();
    if (tid < 64) {
        float s = 0.f;
        #pragma unroll
        for (int r = 0; r < 8; r++) s += ksred[r][tid];
        ksum[bh * 64 + tid] = s;
    }
}

// ---------------- attn_out[t, h*64+j] = (qf_th @ Kmat[bh]) / (qf_th . ksum[bh] + 1e-5) ----
__global__ __launch_bounds__(256) void attn_out_k(const bf16t* __restrict__ qf,
                                                  const float* __restrict__ Kmat,
                                                  const float* __restrict__ ksum,
                                                  bf16t* __restrict__ out) {
    int t = blockIdx.x, tid = threadIdx.x;
    int b = t >> 10;
    __shared__ float q[16 * 65];
    __shared__ float dinv[16];
    for (int i = tid; i < 1024; i += 256) {
        int h = i >> 6, e = i & 63;
        q[h * 65 + e] = __bfloat162float(qf[(size_t)t * 1024 + i]);
    }
    __syncthreads();
    if (tid < 16) {
        int bh = b * 16 + tid;
        float d = 0.f;
        for (int e = 0; e < 64; e++) d += q[tid * 65 + e] * ksum[bh * 64 + e];
        dinv[tid] = 1.f / (d + 1e-5f);
    }
    __syncthreads();
    int h = tid >> 4, j0 = (tid & 15) * 4;
    const float* Km = Kmat + (size_t)(b * 16 + h) * 4096;
    float a0 = 0.f, a1 = 0.f, a2 = 0.f, a3 = 0.f;
    for (int e = 0; e < 64; e++) {
        float qe = q[h * 65 + e];
        const float* kr = Km + e * 64 + j0;
        a0 += qe * kr[0]; a1 += qe * kr[1]; a2 += qe * kr[2]; a3 += qe * kr[3];
    }
    float di = dinv[h];
    size_t ob = (size_t)t * 1024 + h * 64 + j0;
    out[ob + 0] = __float2bfloat16(a0 * di);
    out[ob + 1] = __float2bfloat16(a1 * di);
    out[ob + 2] = __float2bfloat16(a2 * di);
    out[ob + 3] = __float2bfloat16(a3 * di);
}

// ======================= host =======================
#define LAUNCH_GEMM128(MODE, TCT, TADDT, A_, Bt_, bias_, add_, C_, M_, N_, K_, ldC_)         \
    do {                                                                                     \
        int tiles__ = ((M_) >> 7) * ((N_) >> 7);                                             \
        gemm128_k<MODE, TCT, TADDT><<<tiles__, 256, 0, stream>>>(                            \
            (const bf16t*)(A_), (const bf16t*)(Bt_), (const float*)(bias_),                  \
            (const TADDT*)(add_), (TCT*)(C_), (M_), (N_), (K_), (ldC_));                     \
    } while (0)

extern "C" void kernel_launch(void* const* d_in, const int* in_sizes, int n_in,
                              void* d_out, int out_size, void* d_ws, size_t ws_size,
                              hipStream_t stream) {
    (void)in_sizes; (void)n_in;
    const float* x    = (const float*)d_in[0];
    const float* ln1g = (const float*)d_in[1];
    const float* ln1b = (const float*)d_in[2];
    const float* ln2g = (const float*)d_in[3];
    const float* ln2b = (const float*)d_in[4];
    const float* Wq  = (const float*)d_in[5];  const float* bq  = (const float*)d_in[6];
    const float* Wk  = (const float*)d_in[7];  const float* bk  = (const float*)d_in[8];
    const float* Wv  = (const float*)d_in[9];  const float* bv  = (const float*)d_in[10];
    const float* Wf  = (const float*)d_in[11]; const float* bWf = (const float*)d_in[12];
    const float* Wr1 = (const float*)d_in[13]; const float* br1 = (const float*)d_in[14];
    const float* Wr2 = (const float*)d_in[15]; const float* br2 = (const float*)d_in[16];
    const float* Wip = (const float*)d_in[17]; const float* bip = (const float*)d_in[18];
    const float* Wtq = (const float*)d_in[19]; const float* btq = (const float*)d_in[20];
    const float* Wtk = (const float*)d_in[21]; const float* btk = (const float*)d_in[22];
    const float* Wtv = (const float*)d_in[23]; const float* btv = (const float*)d_in[24];
    const float* lnpg= (const float*)d_in[25]; const float* lnpb= (const float*)d_in[26];
    const float* Wl1 = (const float*)d_in[27]; const float* bl1 = (const float*)d_in[28];
    const float* Wl2 = (const float*)d_in[29]; const float* bl2 = (const float*)d_in[30];
    const float* Wsp = (const float*)d_in[31]; const float* bsp = (const float*)d_in[32];

    char* ws = (char*)d_ws;
    size_t off = 0;
    auto alloc = [&](size_t bytes) -> char* {
        off = (off + 255) & ~(size_t)255;
        char* p = ws + off;
        off += bytes;
        return p;
    };
    const size_t T = 4096, TS = 131072;
    const size_t MB8 = T * 1024 * 2, MB16 = T * 2048 * 2;
    bf16t* R_xn   = (bf16t*)alloc(MB8);    // xn -> hbuf
    bf16t* R_h1   = (bf16t*)alloc(MB8);    // qf
    bf16t* R_kv0  = (bf16t*)alloc(MB16);   // kv0 -> WfT/Wr1T/Wr2T (tail)
    bf16t* R_inp  = (bf16t*)alloc(MB16);   // inp -> attn_out
    bf16t* R_kk   = (bf16t*)alloc(MB16);   // kk -> slotsO
    bf16t* R_vv   = (bf16t*)alloc(MB16);   // vvT -> res (fp32, 16MB)
    bf16t* R_sl   = (bf16t*)alloc(MB16);   // slots(final) -> r1
    bf16t* Wcat   = (bf16t*)alloc(5120 * 1024 * 2); // concat proj weights
    bf16t* WtkvT = (bf16t*)alloc(128 * 64 * 2);
    bf16t* WtqI = (bf16t*)alloc(64 * 128 * 2);
    bf16t* Wl1T = (bf16t*)alloc(128 * 64 * 2);
    bf16t* Wl2T = (bf16t*)alloc(64 * 128 * 2);
    bf16t* WspT = (bf16t*)alloc(64 * 128 * 2);
    float* bcat = (float*)alloc(5120 * 4);
    float* bcat2 = (float*)alloc(128 * 4);
    float* Kmat = (float*)alloc(64 * 4096 * 4);
    float* ksum = (float*)alloc(64 * 64 * 4);

    if (off > ws_size) {
        fill_k<<<(out_size + 255) / 256, 256, 0, stream>>>((float*)d_out, out_size, 1000.f);
        return;
    }
    float* R_res = (float*)R_vv;   // fp32 res overlays vvT after slot phase
    // tail weight transposes overlay dead kv0 (16 MB >= 10 MB)
    bf16t* WfT  = R_kv0;                        // 1024x1024
    bf16t* Wr1T = R_kv0 + (size_t)1024 * 1024;  // 2048x1024 rows (N=2048,K=1024)
    bf16t* Wr2T = R_kv0 + (size_t)3072 * 1024;  // 1024x2048

    small_prep_k<<<7, 256, 0, stream>>>(Wtk, Wtv, Wtq, Wl1, Wl2, Wsp, bk, bv, bip, bq, btk, btv,
                                        WtkvT, WtqI, Wl1T, Wl2T, WspT, bcat, bcat2);

    // LN1 (fp32 x -> bf16 xn)
    ln_kernel<<<4096, 256, 0, stream>>>(x, ln1g, ln1b, R_xn);

    // all 4 projection-weight transposes in ONE launch: rows [Wk | Wv | Wip | Wq]
    multi_transpose_k<<<5120, 256, 0, stream>>>(
        Wk, Wv, Wip, Wq,
        Wcat, Wcat + (size_t)1024 * 1024, Wcat + (size_t)2048 * 1024, Wcat + (size_t)4096 * 1024,
        1024, 1024, 1024, 1024, 1024, 2048, 1024, 1024,
        1024, 2048, 4096);

    // merged projection: kv0, inp, qf in one launch (1280 blocks)
    gemm_proj_k<<<1280, 256, 0, stream>>>(R_xn, Wcat, bcat, R_kv0, R_inp, R_h1);

    // kk = feat(...) and vvT in ONE launch
    gemm_kv_k<<<1024, 256, 0, stream>>>(R_inp, WtkvT, bcat2, R_kk, R_vv);

    // fused slot loop (3 iterations), one wave per token
    slot_all_k<<<1024, 256, 0, stream>>>(R_kv0, R_kk, R_vv, WtqI, btq, lnpg, lnpb,
                                         Wl1T, bl1, Wl2T, bl2, R_sl, 0);

    // slotsO = [kv0|slots]@Wsp + bsp -> R_kk (kk dead)
    gemm_cat_k<<<512, 256, 0, stream>>>(R_kv0, R_sl, WspT, bsp, R_kk, 131072);

    // tail weight transposes (Wf, Wr1, Wr2) in ONE launch into dead R_kv0
    multi_transpose_k<<<5120, 256, 0, stream>>>(
        Wf, Wr1, Wr2, Wr2,
        WfT, Wr1T, Wr2T, Wr2T,
        1024, 1024, 1024, 2048, 2048, 1024, 2048, 1024,
        1024, 3072, 5120);

    // linear attention: Kmat/ksum via MFMA, no atomics
    kv_outer_k<<<64, 256, 0, stream>>>(R_kk, Kmat, ksum);

    // attn_out -> R_inp (inp dead)
    attn_out_k<<<4096, 256, 0, stream>>>(R_h1, Kmat, ksum, R_inp);

    // res = x + attn_out@Wf + bf -> fp32 R_res (vvT dead)
    LAUNCH_GEMM128(5, float, float, R_inp, WfT, bWf, x, R_res, 4096, 1024, 1024, 1024);

    // final MLP with residual
    ln_kernel<<<4096, 256, 0, stream>>>(R_res, ln2g, ln2b, R_xn);   // hbuf (xn dead)
    LAUNCH_GEMM128(4, bf16t, bf16t, R_xn, Wr1T, br1, nullptr, R_sl, 4096, 2048, 1024, 2048);
    LAUNCH_GEMM128(5, float, float, R_sl, Wr2T, br2, R_res, (float*)d_out, 4096, 1024, 2048, 1024);
}